// Round 8
// baseline (1222.512 us; speedup 1.0000x reference)
//
#include <hip/hip_runtime.h>
#include <math.h>

#define H 1536
#define E 512
#define T 48
#define S 32
#define V 128
#define NB 256
#define BT 512      // 8 waves
#define NWV 8
#define JPB 6       // h indices per block
#define ROWS 24     // 4*JPB gate rows per block (per matrix)
#define RPW 3       // rows per wave per matrix
#define CHK 24      // floats per lane chunk (1536/64)
// dynamic LDS: whh2 (64 lanes * 145 float4) + h1 chunks (64*7 f4) + h2 chunks
#define WHH2_B   (64 * 145 * 16)          // 148480
#define HBUF_B   (64 * 7 * 16)            // 7168
#define DYN_LDS  (WHH2_B + 2 * HBUF_B)    // 162816

__device__ __forceinline__ float sigf(float x) { return 1.0f / (1.0f + expf(-x)); }
__device__ __forceinline__ float wred(float acc) {
#pragma unroll
    for (int off = 32; off; off >>= 1) acc += __shfl_down(acc, off);
    return acc;
}

// Loads: relaxed agent-scope (cache-bypassing, proven fresh rounds 3-7).
#define GLD(p)    __hip_atomic_load((p), __ATOMIC_RELAXED, __HIP_MEMORY_SCOPE_AGENT)
// Publishes: atomic RMW -> executed at the memory endpoint, NOT write-combined.
// Theory under test: plain relaxed stores sit in WC buffers ~10us before
// becoming visible; RMWs are prompt.
#define GSTF(p, v) (void)__hip_atomic_exchange((unsigned*)(p), __float_as_uint(v), \
                        __ATOMIC_RELAXED, __HIP_MEMORY_SCOPE_AGENT)
#define GMAX(p, v) (void)__hip_atomic_fetch_max((p), (v), \
                        __ATOMIC_RELAXED, __HIP_MEMORY_SCOPE_AGENT)

// Distributed-arrival/release barrier; publishes via atomic RMW.
__device__ __forceinline__ void gbar(unsigned* flags, unsigned* rel, unsigned& gen) {
    __syncthreads();
    gen++;
    if (blockIdx.x == 0) {
        if (threadIdx.x < 64) {
            const int i0 = threadIdx.x * 4;
            for (;;) {
                unsigned a0 = (i0 == 0) ? gen : GLD(&flags[(i0 + 0) * 16]);
                unsigned a1 = GLD(&flags[(i0 + 1) * 16]);
                unsigned a2 = GLD(&flags[(i0 + 2) * 16]);
                unsigned a3 = GLD(&flags[(i0 + 3) * 16]);
                bool ok = (a0 >= gen) && (a1 >= gen) && (a2 >= gen) && (a3 >= gen);
                if (__all(ok)) break;
                __builtin_amdgcn_s_sleep(1);
            }
#pragma unroll
            for (int k = 0; k < 4; ++k) GMAX(&rel[(i0 + k) * 16], gen);
        }
    } else {
        if (threadIdx.x == 0) {
            GMAX(&flags[blockIdx.x * 16], gen);
            while (GLD(&rel[blockIdx.x * 16]) < gen) __builtin_amdgcn_s_sleep(1);
        }
    }
    __syncthreads();
}

__global__ void init_kernel(unsigned* u) {
    for (int i = threadIdx.x; i < 8192; i += 256) u[i] = 0u;   // rel + flags
}

// ws words: [0..4096) rel | [4096..8192) flags | [8192) h1g[H] | h2g[H] |
//           [16384) xw1g: NB * V * 24 floats
__global__ __launch_bounds__(BT, 2) void nas_persist(
    const int* __restrict__ input_id, const float* __restrict__ emb,
    const float* __restrict__ Wih1, const float* __restrict__ Whh1,
    const float* __restrict__ bih1, const float* __restrict__ bhh1,
    const float* __restrict__ Wih2, const float* __restrict__ Whh2,
    const float* __restrict__ bih2, const float* __restrict__ bhh2,
    const float* __restrict__ Wout, const float* __restrict__ bout,
    float* __restrict__ out, float* __restrict__ ws)
{
    const int b = blockIdx.x, tid = threadIdx.x;
    const int wave = tid >> 6, lane = tid & 63;

    unsigned* rel   = (unsigned*)ws;
    unsigned* flags = (unsigned*)ws + 4096;
    float* h1g  = ws + 8192;
    float* h2g  = ws + 8192 + H;
    float* xw1g = ws + 16384 + (size_t)b * (V * ROWS);

    extern __shared__ char dyn_lds[];
    float4* whh2s = (float4*)dyn_lds;                       // [l*145 + k*6 + j]
    float*  h1s   = (float*)(dyn_lds + WHH2_B);             // chunked, stride 28
    float*  h2s   = (float*)(dyn_lds + WHH2_B + HBUF_B);

    __shared__ float gacc1[ROWS], g2f[ROWS], bsum2[ROWS], zlog[S], xr[ROWS];
    __shared__ float c1s[JPB], c2s[JPB];
    __shared__ int   xid_s;

    unsigned gen = 0;

    // ---------------- prologue ----------------
    if (tid < JPB) { c1s[tid] = 0.f; c2s[tid] = 0.f; }
    if (tid < ROWS) {
        int r = (tid / JPB) * H + b * JPB + (tid % JPB);
        bsum2[tid] = bih2[r] + bhh2[r];
    }
    if (tid == 0) xid_s = *input_id;

    // ---- xw1 table -> global ws (uses whh2s region as emb staging) ----
    {
        const int k0 = wave * RPW;
        float4 wiA[RPW], wiB[RPW];
        float  bs[RPW];
#pragma unroll
        for (int i = 0; i < RPW; ++i) {
            int k = k0 + i;
            int r = (k / JPB) * H + b * JPB + (k % JPB);
            const float4* w = (const float4*)(Wih1 + (size_t)r * E);
            wiA[i] = w[lane]; wiB[i] = w[lane + 64];
            bs[i]  = bih1[r] + bhh1[r];
        }
        float4* stage = (float4*)dyn_lds;                   // 2048 f4 = 32 KB
        for (int ch = 0; ch < 8; ++ch) {
            const float4* src = (const float4*)(emb + (size_t)ch * 16 * E);
            for (int m = tid; m < 2048; m += BT) stage[m] = src[m];
            __syncthreads();
            for (int vv = 0; vv < 16; ++vv) {
                float4 ea = stage[vv * 128 + lane];
                float4 eb = stage[vv * 128 + 64 + lane];
#pragma unroll
                for (int i = 0; i < RPW; ++i) {
                    float a = wiA[i].x * ea.x + wiA[i].y * ea.y + wiA[i].z * ea.z + wiA[i].w * ea.w
                            + wiB[i].x * eb.x + wiB[i].y * eb.y + wiB[i].z * eb.z + wiB[i].w * eb.w;
                    a = wred(a);
                    if (lane == 0) xw1g[(ch * 16 + vv) * ROWS + (k0 + i)] = a + bs[i];
                }
            }
            __syncthreads();
        }
    }

    // ---- Whh2 -> LDS (lane-chunked, odd-f4 stride 145) ----
    for (int k = 0; k < ROWS; ++k) {
        int r = (k / JPB) * H + b * JPB + (k % JPB);
        const float4* src = (const float4*)(Whh2 + (size_t)r * H);
        if (tid < 384) {
            int l = tid / 6, j = tid % 6;
            whh2s[l * 145 + k * 6 + j] = src[tid];
        }
    }
    __syncthreads();

    // ---- Whh1 + Wih2 rows -> registers (144 VGPRs/thread) ----
    float w1[RPW][CHK], w2[RPW][CHK];
#pragma unroll
    for (int i = 0; i < RPW; ++i) {
        int k = wave * RPW + i;
        int r = (k / JPB) * H + b * JPB + (k % JPB);
        const float4* p1 = (const float4*)(Whh1 + (size_t)r * H) + lane * 6;
        const float4* p2 = (const float4*)(Wih2 + (size_t)r * H) + lane * 6;
#pragma unroll
        for (int j = 0; j < 6; ++j) {
            float4 v1 = p1[j], v2 = p2[j];
            w1[i][4 * j + 0] = v1.x; w1[i][4 * j + 1] = v1.y;
            w1[i][4 * j + 2] = v1.z; w1[i][4 * j + 3] = v1.w;
            w2[i][4 * j + 0] = v2.x; w2[i][4 * j + 1] = v2.y;
            w2[i][4 * j + 2] = v2.z; w2[i][4 * j + 3] = v2.w;
        }
    }

    float h2c[CHK];
#pragma unroll
    for (int k = 0; k < CHK; ++k) h2c[k] = 0.f;     // h2(-1) = 0

    // ---- initial cell1 (h1(-1)=0, c1(-1)=0) ----
    __syncthreads();
    if (tid < ROWS) xr[tid] = xw1g[xid_s * ROWS + tid];
    __syncthreads();
    if (tid < JPB) {
        float gi = xr[tid], gg = xr[2 * JPB + tid], go = xr[3 * JPB + tid];
        float cn = sigf(gi) * tanhf(gg);
        c1s[tid] = cn;
        GSTF(h1g + b * JPB + tid, sigf(go) * tanhf(cn));
    }
    gbar(flags, rel, gen);

    for (int t = 0; t < T; ++t) {
        // ---------- phase X: 3 HxH matvecs + cell2 pointwise ----------
        for (int i = tid; i < H; i += BT)
            h1s[(i / CHK) * 28 + (i % CHK)] = GLD(h1g + i);
        __syncthreads();

        float h1c[CHK];
        {
            const float4* hp = (const float4*)h1s + lane * 7;
#pragma unroll
            for (int j = 0; j < 6; ++j) {
                float4 v = hp[j];
                h1c[4 * j + 0] = v.x; h1c[4 * j + 1] = v.y;
                h1c[4 * j + 2] = v.z; h1c[4 * j + 3] = v.w;
            }
        }
        float a1[RPW], a2[RPW];
#pragma unroll
        for (int i = 0; i < RPW; ++i) { a1[i] = 0.f; a2[i] = 0.f; }
#pragma unroll
        for (int k = 0; k < CHK; ++k) {
            float h = h1c[k];
#pragma unroll
            for (int i = 0; i < RPW; ++i) {
                a1[i] += w1[i][k] * h;
                a2[i] += w2[i][k] * h;
            }
        }
#pragma unroll
        for (int i = 0; i < RPW; ++i) {
            int k = wave * RPW + i;
            const float4* wp = whh2s + lane * 145 + k * 6;
            float ah = 0.f;
#pragma unroll
            for (int j = 0; j < 6; ++j) {
                float4 v = wp[j];
                ah += v.x * h2c[4 * j + 0] + v.y * h2c[4 * j + 1]
                    + v.z * h2c[4 * j + 2] + v.w * h2c[4 * j + 3];
            }
            float s1 = wred(a1[i]);
            float s2 = wred(a2[i] + ah);
            if (lane == 0) {
                gacc1[k] = s1;
                g2f[k]   = s2 + bsum2[k];
            }
        }
        __syncthreads();
        if (tid < JPB) {
            float gi = g2f[tid],           gf = g2f[JPB + tid];
            float gg = g2f[2 * JPB + tid], go = g2f[3 * JPB + tid];
            float cn = sigf(gf) * c2s[tid] + sigf(gi) * tanhf(gg);
            c2s[tid] = cn;
            GSTF(h2g + b * JPB + tid, sigf(go) * tanhf(cn));
        }
        gbar(flags, rel, gen);

        // ---------- phase Y: head (redundant) + cell1 pointwise ----------
        for (int i = tid; i < H; i += BT)
            h2s[(i / CHK) * 28 + (i % CHK)] = GLD(h2g + i);
        __syncthreads();
        {
            const float4* hp = (const float4*)h2s + lane * 7;
#pragma unroll
            for (int j = 0; j < 6; ++j) {
                float4 v = hp[j];
                h2c[4 * j + 0] = v.x; h2c[4 * j + 1] = v.y;
                h2c[4 * j + 2] = v.z; h2c[4 * j + 3] = v.w;
            }
        }
#pragma unroll
        for (int q = 0; q < 4; ++q) {
            int s = wave * 4 + q;
            const float4* wo = (const float4*)(Wout + ((size_t)t * S + s) * H) + lane * 6;
            float acc = 0.f;
#pragma unroll
            for (int j = 0; j < 6; ++j) {
                float4 v = wo[j];
                acc += v.x * h2c[4 * j + 0] + v.y * h2c[4 * j + 1]
                     + v.z * h2c[4 * j + 2] + v.w * h2c[4 * j + 3];
            }
            acc = wred(acc);
            if (lane == 0) zlog[s] = acc + bout[t * S + s];
        }
        __syncthreads();
        if (wave == 0) {
            float z = (lane < S) ? zlog[lane] : -1e30f;
            float v = z; int idx = (lane < S) ? lane : 9999;
#pragma unroll
            for (int off = 32; off; off >>= 1) {
                float ov = __shfl_xor(v, off); int oi = __shfl_xor(idx, off);
                if (ov > v || (ov == v && oi < idx)) { v = ov; idx = oi; }
            }
            float e = (lane < S) ? expf(z - v) : 0.f;
#pragma unroll
            for (int off = 32; off; off >>= 1) e += __shfl_xor(e, off);
            if (lane == 0) xid_s = (t & 3) * S + idx;
            if (b == 0 && lane < S) out[(size_t)t * S + lane] = z - v - logf(e);
        }
        __syncthreads();
        if (tid < ROWS) xr[tid] = xw1g[xid_s * ROWS + tid];
        __syncthreads();
        if (tid < JPB) {
            float gi = gacc1[tid]           + xr[tid];
            float gf = gacc1[JPB + tid]     + xr[JPB + tid];
            float gg = gacc1[2 * JPB + tid] + xr[2 * JPB + tid];
            float go = gacc1[3 * JPB + tid] + xr[3 * JPB + tid];
            float cn = sigf(gf) * c1s[tid] + sigf(gi) * tanhf(gg);
            c1s[tid] = cn;
            GSTF(h1g + b * JPB + tid, sigf(go) * tanhf(cn));
        }
        gbar(flags, rel, gen);
    }
}

extern "C" void kernel_launch(void* const* d_in, const int* in_sizes, int n_in,
                              void* d_out, int out_size, void* d_ws, size_t ws_size,
                              hipStream_t stream) {
    const int*   input_id = (const int*)d_in[0];
    const float* emb  = (const float*)d_in[1];
    const float* Wih1 = (const float*)d_in[2];
    const float* Whh1 = (const float*)d_in[3];
    const float* bih1 = (const float*)d_in[4];
    const float* bhh1 = (const float*)d_in[5];
    const float* Wih2 = (const float*)d_in[6];
    const float* Whh2 = (const float*)d_in[7];
    const float* bih2 = (const float*)d_in[8];
    const float* bhh2 = (const float*)d_in[9];
    const float* Wout = (const float*)d_in[10];
    const float* bout = (const float*)d_in[11];
    float* out = (float*)d_out;
    float* ws  = (float*)d_ws;

    init_kernel<<<1, 256, 0, stream>>>((unsigned*)ws);

    void* args[] = { (void*)&input_id, (void*)&emb,
                     (void*)&Wih1, (void*)&Whh1, (void*)&bih1, (void*)&bhh1,
                     (void*)&Wih2, (void*)&Whh2, (void*)&bih2, (void*)&bhh2,
                     (void*)&Wout, (void*)&bout, (void*)&out, (void*)&ws };
    hipLaunchCooperativeKernel((void*)nas_persist, dim3(NB), dim3(BT), args,
                               DYN_LDS, stream);
}

// Round 9
// 1175.806 us; speedup vs baseline: 1.0397x; 1.0397x over previous
//
#include <hip/hip_runtime.h>
#include <math.h>

#define H 1536
#define E 512
#define T 48
#define S 32
#define V 128
#define NB 256
#define BT 512      // 8 waves
#define JPB 6       // h indices per block
#define ROWS 24     // 4*JPB gate rows per block (per matrix)
#define RPW 3       // rows per wave per matrix
#define CHK 24      // floats per lane chunk (1536/64)
// dynamic LDS: whh2 (64 lanes * 145 float4) + one shared h-gather buffer
#define WHH2_B   (64 * 145 * 16)          // 148480
#define HBUF_B   (64 * 7 * 16)            // 7168
#define DYN_LDS  (WHH2_B + HBUF_B)        // 155648

__device__ __forceinline__ float sigf(float x) { return 1.0f / (1.0f + expf(-x)); }
__device__ __forceinline__ float wred(float acc) {
#pragma unroll
    for (int off = 32; off; off >>= 1) acc += __shfl_down(acc, off);
    return acc;
}

#define GLD(p)    __hip_atomic_load((p), __ATOMIC_RELAXED, __HIP_MEMORY_SCOPE_AGENT)
#define GST(p, v) __hip_atomic_store((p), (v), __ATOMIC_RELAXED, __HIP_MEMORY_SCOPE_AGENT)

// Distributed-arrival/release barrier (rounds 5-8; mechanism proven neutral
// and correct). Data-before-flag: __syncthreads drains vmcnt before s_barrier.
__device__ __forceinline__ void gbar(unsigned* flags, unsigned* rel, unsigned& gen) {
    __syncthreads();
    gen++;
    if (blockIdx.x == 0) {
        if (threadIdx.x < 64) {
            const int i0 = threadIdx.x * 4;
            for (;;) {
                unsigned a0 = (i0 == 0) ? gen : GLD(&flags[(i0 + 0) * 16]);
                unsigned a1 = GLD(&flags[(i0 + 1) * 16]);
                unsigned a2 = GLD(&flags[(i0 + 2) * 16]);
                unsigned a3 = GLD(&flags[(i0 + 3) * 16]);
                bool ok = (a0 >= gen) && (a1 >= gen) && (a2 >= gen) && (a3 >= gen);
                if (__all(ok)) break;
                __builtin_amdgcn_s_sleep(1);
            }
#pragma unroll
            for (int k = 0; k < 4; ++k) GST(&rel[(i0 + k) * 16], gen);
        }
    } else {
        if (threadIdx.x == 0) {
            GST(&flags[blockIdx.x * 16], gen);
            while (GLD(&rel[blockIdx.x * 16]) < gen) __builtin_amdgcn_s_sleep(1);
        }
    }
    __syncthreads();
}

__global__ void init_kernel(unsigned* u) {
    for (int i = threadIdx.x; i < 8192; i += 256) u[i] = 0u;   // rel + flags
}

// ws words: [0..4096) rel | [4096..8192) flags |
//   [8192) h2g parity0 [H] | parity1 [H] |
//   [16384) cand parity0 [S*H] | parity1 [S*H] |
//   [114688) xw1g: NB * V * 24
__global__ __launch_bounds__(BT, 2) void nas_persist(
    const int* __restrict__ input_id, const float* __restrict__ emb,
    const float* __restrict__ Wih1, const float* __restrict__ Whh1,
    const float* __restrict__ bih1, const float* __restrict__ bhh1,
    const float* __restrict__ Wih2, const float* __restrict__ Whh2,
    const float* __restrict__ bih2, const float* __restrict__ bhh2,
    const float* __restrict__ Wout, const float* __restrict__ bout,
    float* __restrict__ out, float* __restrict__ ws)
{
    const int b = blockIdx.x, tid = threadIdx.x;
    const int wave = tid >> 6, lane = tid & 63;

    unsigned* rel   = (unsigned*)ws;
    unsigned* flags = (unsigned*)ws + 4096;
    float* h2gp[2]  = { ws + 8192, ws + 8192 + H };
    float* candp[2] = { ws + 16384, ws + 16384 + S * H };
    float* xw1g = ws + 114688 + (size_t)b * (V * ROWS);

    extern __shared__ char dyn_lds[];
    float4* whh2s = (float4*)dyn_lds;                 // [lane*145 + row*6 + j]
    float*  hbuf  = (float*)(dyn_lds + WHH2_B);       // chunked, stride 28

    __shared__ float gacc1[ROWS], gaccH[ROWS], g2f[ROWS], bsum2[ROWS], zlog[S];
    __shared__ float c1s[JPB], c2s[JPB], c1cand[S * JPB];
    __shared__ int   xid_s, pred_s;

    unsigned gen = 0;

    // ---------------- prologue ----------------
    if (tid < JPB) { c2s[tid] = 0.f; GST(h2gp[0] + b * JPB + tid, 0.f); }
    if (tid < ROWS) {
        int r = (tid / JPB) * H + b * JPB + (tid % JPB);
        bsum2[tid] = bih2[r] + bhh2[r];
        gaccH[tid] = 0.f;                 // Whh2 @ h2(-1) = 0 for round 0
    }
    if (tid == 0) xid_s = *input_id;

    // ---- xw1 table -> global ws (uses whh2s region as emb staging) ----
    {
        const int k0 = wave * RPW;
        float4 wiA[RPW], wiB[RPW];
        float  bs[RPW];
#pragma unroll
        for (int i = 0; i < RPW; ++i) {
            int k = k0 + i;
            int r = (k / JPB) * H + b * JPB + (k % JPB);
            const float4* w = (const float4*)(Wih1 + (size_t)r * E);
            wiA[i] = w[lane]; wiB[i] = w[lane + 64];
            bs[i]  = bih1[r] + bhh1[r];
        }
        float4* stage = (float4*)dyn_lds;             // 2048 f4 = 32 KB
        for (int ch = 0; ch < 8; ++ch) {
            const float4* src = (const float4*)(emb + (size_t)ch * 16 * E);
            for (int m = tid; m < 2048; m += BT) stage[m] = src[m];
            __syncthreads();
            for (int vv = 0; vv < 16; ++vv) {
                float4 ea = stage[vv * 128 + lane];
                float4 eb = stage[vv * 128 + 64 + lane];
#pragma unroll
                for (int i = 0; i < RPW; ++i) {
                    float a = wiA[i].x * ea.x + wiA[i].y * ea.y + wiA[i].z * ea.z + wiA[i].w * ea.w
                            + wiB[i].x * eb.x + wiB[i].y * eb.y + wiB[i].z * eb.z + wiB[i].w * eb.w;
                    a = wred(a);
                    if (lane == 0) xw1g[(ch * 16 + vv) * ROWS + (k0 + i)] = a + bs[i];
                }
            }
            __syncthreads();
        }
    }

    // ---- Whh2 -> LDS (lane-chunked, odd-f4 stride 145) ----
    for (int k = 0; k < ROWS; ++k) {
        int r = (k / JPB) * H + b * JPB + (k % JPB);
        const float4* src = (const float4*)(Whh2 + (size_t)r * H);
        if (tid < 384) {
            int l = tid / 6, j = tid % 6;
            whh2s[l * 145 + k * 6 + j] = src[tid];
        }
    }
    __syncthreads();

    // ---- Whh1 + Wih2 rows -> registers ----
    float w1[RPW][CHK], w2[RPW][CHK];
#pragma unroll
    for (int i = 0; i < RPW; ++i) {
        int k = wave * RPW + i;
        int r = (k / JPB) * H + b * JPB + (k % JPB);
        const float4* p1 = (const float4*)(Whh1 + (size_t)r * H) + lane * 6;
        const float4* p2 = (const float4*)(Wih2 + (size_t)r * H) + lane * 6;
#pragma unroll
        for (int j = 0; j < 6; ++j) {
            float4 v1 = p1[j], v2 = p2[j];
            w1[i][4 * j + 0] = v1.x; w1[i][4 * j + 1] = v1.y;
            w1[i][4 * j + 2] = v1.z; w1[i][4 * j + 3] = v1.w;
            w2[i][4 * j + 0] = v2.x; w2[i][4 * j + 1] = v2.y;
            w2[i][4 * j + 2] = v2.z; w2[i][4 * j + 3] = v2.w;
        }
    }
    __syncthreads();

    // ---- h1(0) from xid(0)=input_id (gacc1=0, c1(-1)=0); publish to slot 0 ----
    if (tid < JPB) {
        const float* xr = xw1g + (size_t)xid_s * ROWS;
        float gi = xr[tid], gg = xr[2 * JPB + tid], go = xr[3 * JPB + tid];
        float cn = sigf(gi) * tanhf(gg);
        c1s[tid] = cn;
        GST(candp[0] + b * JPB + tid, sigf(go) * tanhf(cn));   // slot 0, parity 0
    }
    gbar(flags, rel, gen);

    // ---------------- main loop: ONE barrier per round ----------------
    for (int k = 0; k <= T; ++k) {
        // gather h2(k-1) from parity k&1
        {
            const float* src = h2gp[k & 1];
            for (int i = tid; i < H; i += BT)
                hbuf[(i / CHK) * 28 + (i % CHK)] = GLD(src + i);
        }
        __syncthreads();
        float h2c[CHK];
        {
            const float4* hp = (const float4*)hbuf + lane * 7;
#pragma unroll
            for (int j = 0; j < 6; ++j) {
                float4 v = hp[j];
                h2c[4 * j + 0] = v.x; h2c[4 * j + 1] = v.y;
                h2c[4 * j + 2] = v.z; h2c[4 * j + 3] = v.w;
            }
        }
        __syncthreads();   // hbuf free for h1 gather

        int psel = 0;
        if (k > 0) {
            // head: logits(k-1) (redundant per block)
#pragma unroll
            for (int q = 0; q < 4; ++q) {
                int s = wave * 4 + q;
                const float4* wo = (const float4*)(Wout + ((size_t)(k - 1) * S + s) * H) + lane * 6;
                float acc = 0.f;
#pragma unroll
                for (int j = 0; j < 6; ++j) {
                    float4 v = wo[j];
                    acc += v.x * h2c[4 * j + 0] + v.y * h2c[4 * j + 1]
                         + v.z * h2c[4 * j + 2] + v.w * h2c[4 * j + 3];
                }
                acc = wred(acc);
                if (lane == 0) zlog[s] = acc + bout[(k - 1) * S + s];
            }
            // Whh2 @ h2(k-1) dots (xid-independent, fill gaccH)
#pragma unroll
            for (int i = 0; i < RPW; ++i) {
                int kk = wave * RPW + i;
                const float4* wp = whh2s + lane * 145 + kk * 6;
                float ah = 0.f;
#pragma unroll
                for (int j = 0; j < 6; ++j) {
                    float4 v = wp[j];
                    ah += v.x * h2c[4 * j + 0] + v.y * h2c[4 * j + 1]
                        + v.z * h2c[4 * j + 2] + v.w * h2c[4 * j + 3];
                }
                ah = wred(ah);
                if (lane == 0) gaccH[kk] = ah;
            }
            __syncthreads();
            if (wave == 0) {
                float z = (lane < S) ? zlog[lane] : -1e30f;
                float v = z; int idx = (lane < S) ? lane : 9999;
#pragma unroll
                for (int off = 32; off; off >>= 1) {
                    float ov = __shfl_xor(v, off); int oi = __shfl_xor(idx, off);
                    if (ov > v || (ov == v && oi < idx)) { v = ov; idx = oi; }
                }
                float e = (lane < S) ? expf(z - v) : 0.f;
#pragma unroll
                for (int off = 32; off; off >>= 1) e += __shfl_xor(e, off);
                if (lane == 0) pred_s = idx;
                if (b == 0 && lane < S) out[(size_t)(k - 1) * S + lane] = z - v - logf(e);
            }
            __syncthreads();
            if (k == T) return;                        // out[T-1] written; done
            psel = pred_s;
            if (tid < JPB) c1s[tid] = c1cand[psel * JPB + tid];   // c1(k) select
        }

        // gather h1(k) = selected candidate slice, parity k&1
        {
            const float* src = candp[k & 1] + (size_t)psel * H;
            for (int i = tid; i < H; i += BT)
                hbuf[(i / CHK) * 28 + (i % CHK)] = GLD(src + i);
        }
        __syncthreads();
        float h1c[CHK];
        {
            const float4* hp = (const float4*)hbuf + lane * 7;
#pragma unroll
            for (int j = 0; j < 6; ++j) {
                float4 v = hp[j];
                h1c[4 * j + 0] = v.x; h1c[4 * j + 1] = v.y;
                h1c[4 * j + 2] = v.z; h1c[4 * j + 3] = v.w;
            }
        }
        // D1: Whh1 @ h1(k), Wih2 @ h1(k) (register weights)
        float a1[RPW], a2[RPW];
#pragma unroll
        for (int i = 0; i < RPW; ++i) { a1[i] = 0.f; a2[i] = 0.f; }
#pragma unroll
        for (int kk = 0; kk < CHK; ++kk) {
            float h = h1c[kk];
#pragma unroll
            for (int i = 0; i < RPW; ++i) {
                a1[i] += w1[i][kk] * h;
                a2[i] += w2[i][kk] * h;
            }
        }
#pragma unroll
        for (int i = 0; i < RPW; ++i) {
            int kk = wave * RPW + i;
            float s1 = wred(a1[i]);
            float s2 = wred(a2[i]);
            if (lane == 0) {
                gacc1[kk] = s1;
                g2f[kk]   = s2 + gaccH[kk] + bsum2[kk];
            }
        }
        __syncthreads();

        // P2: h2(k) fragment -> publish to parity (k+1)&1
        if (tid < JPB) {
            float gi = g2f[tid],           gf = g2f[JPB + tid];
            float gg = g2f[2 * JPB + tid], go = g2f[3 * JPB + tid];
            float cn = sigf(gf) * c2s[tid] + sigf(gi) * tanhf(gg);
            c2s[tid] = cn;
            GST(h2gp[(k + 1) & 1] + b * JPB + tid, sigf(go) * tanhf(cn));
        }
        // candidates for h1(k+1): all 32 possible preds; publish fragments
        if (tid < S * JPB) {
            int p = tid / JPB, j = tid % JPB;
            const float* xr = xw1g + (size_t)((k & 3) * S + p) * ROWS;
            float gi = gacc1[j]           + xr[j];
            float gf = gacc1[JPB + j]     + xr[JPB + j];
            float gg = gacc1[2 * JPB + j] + xr[2 * JPB + j];
            float go = gacc1[3 * JPB + j] + xr[3 * JPB + j];
            float cn = sigf(gf) * c1s[j] + sigf(gi) * tanhf(gg);
            c1cand[tid] = cn;
            GST(candp[(k + 1) & 1] + (size_t)p * H + b * JPB + j,
                sigf(go) * tanhf(cn));
        }
        gbar(flags, rel, gen);
    }
}

extern "C" void kernel_launch(void* const* d_in, const int* in_sizes, int n_in,
                              void* d_out, int out_size, void* d_ws, size_t ws_size,
                              hipStream_t stream) {
    const int*   input_id = (const int*)d_in[0];
    const float* emb  = (const float*)d_in[1];
    const float* Wih1 = (const float*)d_in[2];
    const float* Whh1 = (const float*)d_in[3];
    const float* bih1 = (const float*)d_in[4];
    const float* bhh1 = (const float*)d_in[5];
    const float* Wih2 = (const float*)d_in[6];
    const float* Whh2 = (const float*)d_in[7];
    const float* bih2 = (const float*)d_in[8];
    const float* bhh2 = (const float*)d_in[9];
    const float* Wout = (const float*)d_in[10];
    const float* bout = (const float*)d_in[11];
    float* out = (float*)d_out;
    float* ws  = (float*)d_ws;

    init_kernel<<<1, 256, 0, stream>>>((unsigned*)ws);

    void* args[] = { (void*)&input_id, (void*)&emb,
                     (void*)&Wih1, (void*)&Whh1, (void*)&bih1, (void*)&bhh1,
                     (void*)&Wih2, (void*)&Whh2, (void*)&bih2, (void*)&bhh2,
                     (void*)&Wout, (void*)&bout, (void*)&out, (void*)&ws };
    hipLaunchCooperativeKernel((void*)nas_persist, dim3(NB), dim3(BT), args,
                               DYN_LDS, stream);
}